// Round 1
// baseline (740.077 us; speedup 1.0000x reference)
//
#include <hip/hip_runtime.h>

#define HID 64
#define SCAN_B 128
#define SCAN_T 256

// ---------------- CSR build ----------------

__global__ void count_kernel(const int* __restrict__ ei, int E, int* __restrict__ cnt) {
    int stride = gridDim.x * blockDim.x;
    for (int e = blockIdx.x * blockDim.x + threadIdx.x; e < E; e += stride) {
        int d = ei[E + e];  // edge_index[1][e]
        atomicAdd(&cnt[d], 1);
    }
}

__global__ void dinv_kernel(const int* __restrict__ cnt, float* __restrict__ dinv, int N) {
    int stride = gridDim.x * blockDim.x;
    for (int n = blockIdx.x * blockDim.x + threadIdx.x; n < N; n += stride) {
        // deg includes the self-loop -> always >= 1
        dinv[n] = rsqrtf((float)(cnt[n] + 1));
    }
}

__global__ void scan_sum(const int* __restrict__ cnt, int N, int* __restrict__ bsum) {
    int b = blockIdx.x;
    int chunk = (N + SCAN_B - 1) / SCAN_B;
    int lo = b * chunk, hi = min(lo + chunk, N);
    int s = 0;
    for (int i = lo + threadIdx.x; i < hi; i += SCAN_T) s += cnt[i];
    for (int off = 32; off; off >>= 1) s += __shfl_xor(s, off);
    __shared__ int red[SCAN_T / 64];
    int wave = threadIdx.x >> 6, lane = threadIdx.x & 63;
    if (lane == 0) red[wave] = s;
    __syncthreads();
    if (threadIdx.x == 0) {
        int t = 0;
        for (int w = 0; w < SCAN_T / 64; w++) t += red[w];
        bsum[b] = t;
    }
}

__global__ void scan_bsum(const int* __restrict__ bsum, int* __restrict__ bofs) {
    if (blockIdx.x == 0 && threadIdx.x == 0) {
        int r = 0;
        for (int b = 0; b < SCAN_B; b++) { bofs[b] = r; r += bsum[b]; }
    }
}

__global__ void scan_chunk(const int* __restrict__ cnt, int N, const int* __restrict__ bofs,
                           int* __restrict__ row_start, int* __restrict__ cursor) {
    int b = blockIdx.x;
    int chunk = (N + SCAN_B - 1) / SCAN_B;
    int lo = b * chunk, hi = min(lo + chunk, N);
    __shared__ int s[SCAN_T];
    __shared__ int carry;
    if (threadIdx.x == 0) carry = bofs[b];
    __syncthreads();
    for (int base = lo; base < hi; base += SCAN_T) {
        int i = base + threadIdx.x;
        int v = (i < hi) ? cnt[i] : 0;
        s[threadIdx.x] = v;
        __syncthreads();
        for (int off = 1; off < SCAN_T; off <<= 1) {
            int t = (threadIdx.x >= off) ? s[threadIdx.x - off] : 0;
            __syncthreads();
            s[threadIdx.x] += t;
            __syncthreads();
        }
        int incl = s[threadIdx.x];
        int c = carry;
        if (i < hi) {
            int ex = c + incl - v;
            row_start[i] = ex;
            cursor[i] = ex;
        }
        __syncthreads();
        if (threadIdx.x == SCAN_T - 1) carry = c + incl;
        __syncthreads();
    }
}

__global__ void fill_kernel(const int* __restrict__ ei, int E, const float* __restrict__ dinv,
                            int* __restrict__ cursor, int* __restrict__ csr_src,
                            float* __restrict__ csr_w) {
    int stride = gridDim.x * blockDim.x;
    for (int e = blockIdx.x * blockDim.x + threadIdx.x; e < E; e += stride) {
        int s = ei[e];
        int d = ei[E + e];
        int pos = atomicAdd(&cursor[d], 1);
        csr_src[pos] = s;
        csr_w[pos] = dinv[s];
    }
}

// ---------------- Layer 1: scalar propagate + (relu(p*W1+b1)) @ W2 ----------------
// wave per node; lane k owns output feature k

__global__ __launch_bounds__(256) void layer1_kernel(
    const float* __restrict__ x, const int* __restrict__ csr_src, const float* __restrict__ csr_w,
    const int* __restrict__ row_start, const int* __restrict__ cnt, const float* __restrict__ dinv,
    const float* __restrict__ W1, const float* __restrict__ b1, const float* __restrict__ W2,
    float* __restrict__ z1, int N) {
    __shared__ float sW2[HID * HID];
    for (int i = threadIdx.x; i < HID * HID; i += 256) sW2[i] = W2[i];
    __syncthreads();
    int lane = threadIdx.x & 63;
    int n = blockIdx.x * 4 + (threadIdx.x >> 6);
    if (n >= N) return;
    int start = row_start[n], deg = cnt[n];
    float acc = 0.f;
    for (int i = start + lane; i < start + deg; i += 64)
        acc += csr_w[i] * x[csr_src[i]];
    for (int off = 32; off; off >>= 1) acc += __shfl_xor(acc, off);
    float dn = dinv[n];
    float p = dn * (acc + dn * x[n]);
    float h = fmaxf(p * W1[lane] + b1[lane], 0.f);  // h1[n][lane]
    float z = 0.f;
#pragma unroll
    for (int j = 0; j < HID; j++) z += __shfl(h, j) * sW2[j * HID + lane];
    z1[(size_t)n * HID + lane] = z;  // (h1 @ W2)[n][lane]
}

// ---------------- 64-wide propagate (layers 2,3) ----------------
// out = FUSE ? relu(P(zin)+bias) @ W : P(zin)+bias

template <bool FUSE>
__global__ __launch_bounds__(256) void p64_kernel(
    const float* __restrict__ zin, const int* __restrict__ csr_src, const float* __restrict__ csr_w,
    const int* __restrict__ row_start, const int* __restrict__ cnt, const float* __restrict__ dinv,
    const float* __restrict__ bias, const float* __restrict__ W, float* __restrict__ out, int N) {
    __shared__ float sW[FUSE ? HID * HID : 1];
    if (FUSE) {
        for (int i = threadIdx.x; i < HID * HID; i += 256) sW[i] = W[i];
        __syncthreads();
    }
    int lane = threadIdx.x & 63;
    int n = blockIdx.x * 4 + (threadIdx.x >> 6);
    if (n >= N) return;
    int start = row_start[n], deg = cnt[n];
    float acc = 0.f;
    for (int base = 0; base < deg; base += 64) {
        int rem = deg - base;
        int i = start + base + lane;
        int sidx = (lane < rem) ? csr_src[i] : 0;
        float wv = (lane < rem) ? csr_w[i] : 0.f;
        int m = rem < 64 ? rem : 64;
        for (int t = 0; t < m; t++) {
            int ss = __shfl(sidx, t);
            float ww = __shfl(wv, t);
            acc += ww * zin[(size_t)ss * HID + lane];  // coalesced 256B row read
        }
    }
    float dn = dinv[n];
    acc = dn * (acc + dn * zin[(size_t)n * HID + lane]) + bias[lane];
    if (FUSE) {
        float h = fmaxf(acc, 0.f);
        float z = 0.f;
#pragma unroll
        for (int j = 0; j < HID; j++) z += __shfl(h, j) * sW[j * HID + lane];
        out[(size_t)n * HID + lane] = z;
    } else {
        out[(size_t)n * HID + lane] = acc;
    }
}

// ---------------- pooling + head ----------------

__global__ __launch_bounds__(256) void pool_kernel(const float* __restrict__ h,
                                                   const int* __restrict__ batch,
                                                   float* __restrict__ psum, int* __restrict__ pcnt,
                                                   int N) {
    int lane = threadIdx.x & 63;
    int n = blockIdx.x * 4 + (threadIdx.x >> 6);
    if (n >= N) return;
    int g = batch[n];
    atomicAdd(&psum[(size_t)g * HID + lane], h[(size_t)n * HID + lane]);
    if (lane == 0) atomicAdd(&pcnt[g], 1);
}

__global__ void head_kernel(const float* __restrict__ psum, const int* __restrict__ pcnt,
                            const float* __restrict__ dist, const float* __restrict__ sw,
                            const float* __restrict__ Wl, const float* __restrict__ bl,
                            const float* __restrict__ Wl1, const float* __restrict__ bl1,
                            const float* __restrict__ Wl2, const float* __restrict__ bl2,
                            float* __restrict__ out, int G) {
    int g = blockIdx.x * blockDim.x + threadIdx.x;
    if (g >= G) return;
    float invc = 1.f / fmaxf((float)pcnt[g], 1.f);
    float a[5];
#pragma unroll
    for (int k = 0; k < 5; k++) a[k] = bl[k];
    for (int j = 0; j < HID; j++) {
        float p = psum[(size_t)g * HID + j] * invc;
#pragma unroll
        for (int k = 0; k < 5; k++) a[k] += p * Wl[j * 5 + k];
    }
    float g7[7];
#pragma unroll
    for (int k = 0; k < 5; k++) g7[k] = a[k];
    g7[5] = dist[g];
    g7[6] = sw[g];
    float r = bl2[0];
#pragma unroll
    for (int k2 = 0; k2 < 5; k2++) {
        float t = bl1[k2];
#pragma unroll
        for (int j = 0; j < 7; j++) t += g7[j] * Wl1[j * 5 + k2];
        t = fmaxf(t, 0.f);
        r += t * Wl2[k2];
    }
    out[g] = r;
}

// ---------------- launch ----------------

extern "C" void kernel_launch(void* const* d_in, const int* in_sizes, int n_in,
                              void* d_out, int out_size, void* d_ws, size_t ws_size,
                              hipStream_t stream) {
    const float* x    = (const float*)d_in[0];
    const int*   ei   = (const int*)d_in[1];   // edge_index [2,E] (int32 per harness)
    const int*   batch= (const int*)d_in[2];
    const float* dist = (const float*)d_in[3];
    const float* sw   = (const float*)d_in[4];
    const float* W1   = (const float*)d_in[5];
    const float* b1   = (const float*)d_in[6];
    const float* W2   = (const float*)d_in[7];
    const float* b2   = (const float*)d_in[8];
    const float* W3   = (const float*)d_in[9];
    const float* b3   = (const float*)d_in[10];
    const float* Wl   = (const float*)d_in[11];
    const float* bl   = (const float*)d_in[12];
    const float* Wl1  = (const float*)d_in[13];
    const float* bl1  = (const float*)d_in[14];
    const float* Wl2  = (const float*)d_in[15];
    const float* bl2  = (const float*)d_in[16];

    int N = in_sizes[0];
    int E = in_sizes[1] / 2;
    int G = in_sizes[3];

    char* ws = (char*)d_ws;
    size_t off = 0;
    auto alloc = [&](size_t bytes) -> char* {
        char* p = ws + off;
        off += (bytes + 255) & ~(size_t)255;
        return p;
    };
    int*   cnt       = (int*)alloc((size_t)N * 4);
    int*   row_start = (int*)alloc((size_t)N * 4);
    int*   cursor    = (int*)alloc((size_t)N * 4);
    float* dinv      = (float*)alloc((size_t)N * 4);
    int*   bsum      = (int*)alloc(SCAN_B * 4);
    int*   bofs      = (int*)alloc(SCAN_B * 4);
    int*   csr_src   = (int*)alloc((size_t)E * 4);
    float* csr_w     = (float*)alloc((size_t)E * 4);
    float* bufA      = (float*)alloc((size_t)N * HID * 4);
    float* bufB      = (float*)alloc((size_t)N * HID * 4);
    float* psum      = (float*)alloc((size_t)G * HID * 4);
    int*   pcnt      = (int*)alloc((size_t)G * 4);

    hipMemsetAsync(cnt, 0, (size_t)N * 4, stream);
    hipMemsetAsync(psum, 0, (size_t)G * HID * 4, stream);
    hipMemsetAsync(pcnt, 0, (size_t)G * 4, stream);

    count_kernel<<<2048, 256, 0, stream>>>(ei, E, cnt);
    dinv_kernel<<<(N + 255) / 256, 256, 0, stream>>>(cnt, dinv, N);
    scan_sum<<<SCAN_B, SCAN_T, 0, stream>>>(cnt, N, bsum);
    scan_bsum<<<1, 64, 0, stream>>>(bsum, bofs);
    scan_chunk<<<SCAN_B, SCAN_T, 0, stream>>>(cnt, N, bofs, row_start, cursor);
    fill_kernel<<<2048, 256, 0, stream>>>(ei, E, dinv, cursor, csr_src, csr_w);

    int nb = (N + 3) / 4;
    layer1_kernel<<<nb, 256, 0, stream>>>(x, csr_src, csr_w, row_start, cnt, dinv, W1, b1, W2,
                                          bufA, N);
    p64_kernel<true><<<nb, 256, 0, stream>>>(bufA, csr_src, csr_w, row_start, cnt, dinv, b2, W3,
                                             bufB, N);
    p64_kernel<false><<<nb, 256, 0, stream>>>(bufB, csr_src, csr_w, row_start, cnt, dinv, b3,
                                              nullptr, bufA, N);
    pool_kernel<<<nb, 256, 0, stream>>>(bufA, batch, psum, pcnt, N);
    head_kernel<<<(G + 255) / 256, 256, 0, stream>>>(psum, pcnt, dist, sw, Wl, bl, Wl1, bl1, Wl2,
                                                     bl2, (float*)d_out, G);
}

// Round 2
// 629.656 us; speedup vs baseline: 1.1754x; 1.1754x over previous
//
#include <hip/hip_runtime.h>

#define HID 64
#define SCAN_B 128
#define SCAN_T 256

// ---------------- CSR build ----------------

__global__ void count_kernel(const int* __restrict__ ei, int E, int* __restrict__ cnt) {
    int stride = gridDim.x * blockDim.x;
    for (int e = blockIdx.x * blockDim.x + threadIdx.x; e < E; e += stride) {
        int d = ei[E + e];  // edge_index[1][e]
        atomicAdd(&cnt[d], 1);
    }
}

__global__ void dinv_kernel(const int* __restrict__ cnt, float* __restrict__ dinv,
                            const int* __restrict__ batch, int* __restrict__ pcnt, int N) {
    int stride = gridDim.x * blockDim.x;
    for (int n = blockIdx.x * blockDim.x + threadIdx.x; n < N; n += stride) {
        dinv[n] = rsqrtf((float)(cnt[n] + 1));  // deg includes self-loop
        atomicAdd(&pcnt[batch[n]], 1);
    }
}

__global__ void scan_sum(const int* __restrict__ cnt, int N, int* __restrict__ bsum) {
    int b = blockIdx.x;
    int chunk = (N + SCAN_B - 1) / SCAN_B;
    int lo = b * chunk, hi = min(lo + chunk, N);
    int s = 0;
    for (int i = lo + threadIdx.x; i < hi; i += SCAN_T) s += cnt[i];
    for (int off = 32; off; off >>= 1) s += __shfl_xor(s, off);
    __shared__ int red[SCAN_T / 64];
    int wave = threadIdx.x >> 6, lane = threadIdx.x & 63;
    if (lane == 0) red[wave] = s;
    __syncthreads();
    if (threadIdx.x == 0) {
        int t = 0;
        for (int w = 0; w < SCAN_T / 64; w++) t += red[w];
        bsum[b] = t;
    }
}

__global__ void scan_bsum(const int* __restrict__ bsum, int* __restrict__ bofs) {
    if (blockIdx.x == 0 && threadIdx.x == 0) {
        int r = 0;
        for (int b = 0; b < SCAN_B; b++) { bofs[b] = r; r += bsum[b]; }
    }
}

__global__ void scan_chunk(const int* __restrict__ cnt, int N, const int* __restrict__ bofs,
                           int* __restrict__ row_start, int* __restrict__ cursor) {
    int b = blockIdx.x;
    int chunk = (N + SCAN_B - 1) / SCAN_B;
    int lo = b * chunk, hi = min(lo + chunk, N);
    __shared__ int s[SCAN_T];
    __shared__ int carry;
    if (threadIdx.x == 0) carry = bofs[b];
    __syncthreads();
    for (int base = lo; base < hi; base += SCAN_T) {
        int i = base + threadIdx.x;
        int v = (i < hi) ? cnt[i] : 0;
        s[threadIdx.x] = v;
        __syncthreads();
        for (int off = 1; off < SCAN_T; off <<= 1) {
            int t = (threadIdx.x >= off) ? s[threadIdx.x - off] : 0;
            __syncthreads();
            s[threadIdx.x] += t;
            __syncthreads();
        }
        int incl = s[threadIdx.x];
        int c = carry;
        if (i < hi) {
            int ex = c + incl - v;
            row_start[i] = ex;
            cursor[i] = ex;
        }
        __syncthreads();
        if (threadIdx.x == SCAN_T - 1) carry = c + incl;
        __syncthreads();
    }
}

__global__ void fill_kernel(const int* __restrict__ ei, int E, const float* __restrict__ dinv,
                            int* __restrict__ cursor, int2* __restrict__ csr) {
    int stride = gridDim.x * blockDim.x;
    for (int e = blockIdx.x * blockDim.x + threadIdx.x; e < E; e += stride) {
        int s = ei[e];
        int d = ei[E + e];
        int pos = atomicAdd(&cursor[d], 1);
        csr[pos] = make_int2(s, __float_as_int(dinv[s]));
    }
}

// ---------------- quarter-split fused 64x64 matmul ----------------
// h4 holds features [sl*4 .. sl*4+3], replicated across the 4 quarter-waves.
// Returns z4 = (h @ W)[sl*4 .. sl*4+3], replicated across quarters.
__device__ __forceinline__ float4 qmatmul(float4 h4, const float* __restrict__ sW, int q, int sl) {
    float4 z4 = make_float4(0.f, 0.f, 0.f, 0.f);
#pragma unroll
    for (int t = 0; t < 16; t++) {
        int k = (q << 4) + t;                       // this quarter's k-range
        int srclane = 20 * q + (t >> 2);            // lane holding h[k]
        float comp = ((t & 3) == 0) ? h4.x : ((t & 3) == 1) ? h4.y : ((t & 3) == 2) ? h4.z : h4.w;
        float hk = __shfl(comp, srclane);
        const float4 w4 = *reinterpret_cast<const float4*>(&sW[k * HID + sl * 4]);
        z4.x += hk * w4.x; z4.y += hk * w4.y; z4.z += hk * w4.z; z4.w += hk * w4.w;
    }
#pragma unroll
    for (int off = 16; off <= 32; off <<= 1) {
        z4.x += __shfl_xor(z4.x, off);
        z4.y += __shfl_xor(z4.y, off);
        z4.z += __shfl_xor(z4.z, off);
        z4.w += __shfl_xor(z4.w, off);
    }
    return z4;
}

// ---------------- Layer 1: scalar propagate + (relu(p*W1+b1)) @ W2 ----------------

__global__ __launch_bounds__(256) void layer1_kernel(
    const float* __restrict__ x, const int2* __restrict__ csr,
    const int* __restrict__ row_start, const int* __restrict__ cnt, const float* __restrict__ dinv,
    const float* __restrict__ W1, const float* __restrict__ b1, const float* __restrict__ W2,
    float* __restrict__ z1, int N) {
    __shared__ float sW2[HID * HID];
    for (int i = threadIdx.x; i < HID * HID; i += 256) sW2[i] = W2[i];
    __syncthreads();
    int lane = threadIdx.x & 63;
    int q = lane >> 4, sl = lane & 15;
    int n = blockIdx.x * 4 + (threadIdx.x >> 6);
    if (n >= N) return;
    int start = row_start[n], deg = cnt[n];
    float acc = 0.f;
    for (int i = start + lane; i < start + deg; i += 64) {
        int2 ew = csr[i];
        acc += __int_as_float(ew.y) * x[ew.x];
    }
#pragma unroll
    for (int off = 32; off; off >>= 1) acc += __shfl_xor(acc, off);
    float dn = dinv[n];
    float p = dn * (acc + dn * x[n]);  // wave-uniform
    const float4 w14 = *reinterpret_cast<const float4*>(&W1[sl * 4]);
    const float4 b14 = *reinterpret_cast<const float4*>(&b1[sl * 4]);
    float4 h4;
    h4.x = fmaxf(p * w14.x + b14.x, 0.f);
    h4.y = fmaxf(p * w14.y + b14.y, 0.f);
    h4.z = fmaxf(p * w14.z + b14.z, 0.f);
    h4.w = fmaxf(p * w14.w + b14.w, 0.f);
    float4 z4 = qmatmul(h4, sW2, q, sl);
    if (q == 0) *reinterpret_cast<float4*>(&z1[(size_t)n * HID + sl * 4]) = z4;
}

// ---------------- 64-wide propagate (layers 2,3) ----------------
// Quarter-parallel gather: 4 edges per wave-instruction, float4 per lane.
// FUSE: out = relu(P(zin)+bias) @ W     (layer 2)
// POOL: atomicAdd P(zin)+bias into psum (layer 3 + global pool)

template <bool FUSE, bool POOL>
__global__ __launch_bounds__(256) void p64_kernel(
    const float* __restrict__ zin, const int2* __restrict__ csr,
    const int* __restrict__ row_start, const int* __restrict__ cnt, const float* __restrict__ dinv,
    const float* __restrict__ bias, const float* __restrict__ W,
    float* __restrict__ out, const int* __restrict__ batch, int N) {
    __shared__ float sW[FUSE ? HID * HID : 1];
    if (FUSE) {
        for (int i = threadIdx.x; i < HID * HID; i += 256) sW[i] = W[i];
        __syncthreads();
    }
    int lane = threadIdx.x & 63;
    int q = lane >> 4, sl = lane & 15;
    int n = blockIdx.x * 4 + (threadIdx.x >> 6);
    if (n >= N) return;
    int start = row_start[n], deg = cnt[n];
    float4 acc = make_float4(0.f, 0.f, 0.f, 0.f);
    for (int base = 0; base < deg; base += 64) {
        int m = deg - base; if (m > 64) m = 64;
        int2 ew = (lane < m) ? csr[start + base + lane] : make_int2(0, 0);
        int mt = (m + 3) >> 2;
        for (int t = 0; t < mt; t++) {
            int eidx = (t << 2) + q;
            int ss = __shfl(ew.x, eidx);
            float ww = __int_as_float(__shfl(ew.y, eidx));
            const float4 row =
                *reinterpret_cast<const float4*>(&zin[(size_t)ss * HID + sl * 4]);
            acc.x += ww * row.x; acc.y += ww * row.y; acc.z += ww * row.z; acc.w += ww * row.w;
        }
    }
#pragma unroll
    for (int off = 16; off <= 32; off <<= 1) {
        acc.x += __shfl_xor(acc.x, off);
        acc.y += __shfl_xor(acc.y, off);
        acc.z += __shfl_xor(acc.z, off);
        acc.w += __shfl_xor(acc.w, off);
    }
    float dn = dinv[n];
    const float4 self = *reinterpret_cast<const float4*>(&zin[(size_t)n * HID + sl * 4]);
    const float4 b4 = *reinterpret_cast<const float4*>(&bias[sl * 4]);
    acc.x = dn * (acc.x + dn * self.x) + b4.x;
    acc.y = dn * (acc.y + dn * self.y) + b4.y;
    acc.z = dn * (acc.z + dn * self.z) + b4.z;
    acc.w = dn * (acc.w + dn * self.w) + b4.w;
    if (FUSE) {
        float4 h4;
        h4.x = fmaxf(acc.x, 0.f); h4.y = fmaxf(acc.y, 0.f);
        h4.z = fmaxf(acc.z, 0.f); h4.w = fmaxf(acc.w, 0.f);
        float4 z4 = qmatmul(h4, sW, q, sl);
        if (q == 0) *reinterpret_cast<float4*>(&out[(size_t)n * HID + sl * 4]) = z4;
    } else if (POOL) {
        if (q == 0) {
            int g = batch[n];
            float* p = &out[(size_t)g * HID + sl * 4];
            atomicAdd(p + 0, acc.x);
            atomicAdd(p + 1, acc.y);
            atomicAdd(p + 2, acc.z);
            atomicAdd(p + 3, acc.w);
        }
    } else {
        if (q == 0) *reinterpret_cast<float4*>(&out[(size_t)n * HID + sl * 4]) = acc;
    }
}

// ---------------- head ----------------

__global__ void head_kernel(const float* __restrict__ psum, const int* __restrict__ pcnt,
                            const float* __restrict__ dist, const float* __restrict__ sw,
                            const float* __restrict__ Wl, const float* __restrict__ bl,
                            const float* __restrict__ Wl1, const float* __restrict__ bl1,
                            const float* __restrict__ Wl2, const float* __restrict__ bl2,
                            float* __restrict__ out, int G) {
    int g = blockIdx.x * blockDim.x + threadIdx.x;
    if (g >= G) return;
    float invc = 1.f / fmaxf((float)pcnt[g], 1.f);
    float a[5];
#pragma unroll
    for (int k = 0; k < 5; k++) a[k] = bl[k];
    for (int j = 0; j < HID; j++) {
        float p = psum[(size_t)g * HID + j] * invc;
#pragma unroll
        for (int k = 0; k < 5; k++) a[k] += p * Wl[j * 5 + k];
    }
    float g7[7];
#pragma unroll
    for (int k = 0; k < 5; k++) g7[k] = a[k];
    g7[5] = dist[g];
    g7[6] = sw[g];
    float r = bl2[0];
#pragma unroll
    for (int k2 = 0; k2 < 5; k2++) {
        float t = bl1[k2];
#pragma unroll
        for (int j = 0; j < 7; j++) t += g7[j] * Wl1[j * 5 + k2];
        t = fmaxf(t, 0.f);
        r += t * Wl2[k2];
    }
    out[g] = r;
}

// ---------------- launch ----------------

extern "C" void kernel_launch(void* const* d_in, const int* in_sizes, int n_in,
                              void* d_out, int out_size, void* d_ws, size_t ws_size,
                              hipStream_t stream) {
    const float* x    = (const float*)d_in[0];
    const int*   ei   = (const int*)d_in[1];
    const int*   batch= (const int*)d_in[2];
    const float* dist = (const float*)d_in[3];
    const float* sw   = (const float*)d_in[4];
    const float* W1   = (const float*)d_in[5];
    const float* b1   = (const float*)d_in[6];
    const float* W2   = (const float*)d_in[7];
    const float* b2   = (const float*)d_in[8];
    const float* W3   = (const float*)d_in[9];
    const float* b3   = (const float*)d_in[10];
    const float* Wl   = (const float*)d_in[11];
    const float* bl   = (const float*)d_in[12];
    const float* Wl1  = (const float*)d_in[13];
    const float* bl1  = (const float*)d_in[14];
    const float* Wl2  = (const float*)d_in[15];
    const float* bl2  = (const float*)d_in[16];

    int N = in_sizes[0];
    int E = in_sizes[1] / 2;
    int G = in_sizes[3];

    char* ws = (char*)d_ws;
    size_t off = 0;
    auto alloc = [&](size_t bytes) -> char* {
        char* p = ws + off;
        off += (bytes + 255) & ~(size_t)255;
        return p;
    };
    int*   cnt       = (int*)alloc((size_t)N * 4);
    int*   row_start = (int*)alloc((size_t)N * 4);
    int*   cursor    = (int*)alloc((size_t)N * 4);
    float* dinv      = (float*)alloc((size_t)N * 4);
    int*   bsum      = (int*)alloc(SCAN_B * 4);
    int*   bofs      = (int*)alloc(SCAN_B * 4);
    int2*  csr       = (int2*)alloc((size_t)E * 8);
    float* bufA      = (float*)alloc((size_t)N * HID * 4);
    float* bufB      = (float*)alloc((size_t)N * HID * 4);
    float* psum      = (float*)alloc((size_t)G * HID * 4);
    int*   pcnt      = (int*)alloc((size_t)G * 4);

    hipMemsetAsync(cnt, 0, (size_t)N * 4, stream);
    hipMemsetAsync(psum, 0, (size_t)G * HID * 4, stream);
    hipMemsetAsync(pcnt, 0, (size_t)G * 4, stream);

    count_kernel<<<2048, 256, 0, stream>>>(ei, E, cnt);
    dinv_kernel<<<(N + 255) / 256, 256, 0, stream>>>(cnt, dinv, batch, pcnt, N);
    scan_sum<<<SCAN_B, SCAN_T, 0, stream>>>(cnt, N, bsum);
    scan_bsum<<<1, 64, 0, stream>>>(bsum, bofs);
    scan_chunk<<<SCAN_B, SCAN_T, 0, stream>>>(cnt, N, bofs, row_start, cursor);
    fill_kernel<<<2048, 256, 0, stream>>>(ei, E, dinv, cursor, csr);

    int nb = (N + 3) / 4;
    layer1_kernel<<<nb, 256, 0, stream>>>(x, csr, row_start, cnt, dinv, W1, b1, W2, bufA, N);
    p64_kernel<true, false><<<nb, 256, 0, stream>>>(bufA, csr, row_start, cnt, dinv, b2, W3,
                                                    bufB, nullptr, N);
    p64_kernel<false, true><<<nb, 256, 0, stream>>>(bufB, csr, row_start, cnt, dinv, b3, nullptr,
                                                    psum, batch, N);
    head_kernel<<<(G + 255) / 256, 256, 0, stream>>>(psum, pcnt, dist, sw, Wl, bl, Wl1, bl1, Wl2,
                                                     bl2, (float*)d_out, G);
}

// Round 3
// 493.010 us; speedup vs baseline: 1.5011x; 1.2772x over previous
//
#include <hip/hip_runtime.h>

#define HID 64
#define SCAN_B 128
#define SCAN_T 256

// ---------------- CSR build ----------------

__global__ void count_kernel(const int* __restrict__ ei, int E, int* __restrict__ cnt) {
    int stride = gridDim.x * blockDim.x;
    for (int e = blockIdx.x * blockDim.x + threadIdx.x; e < E; e += stride) {
        int d = ei[E + e];  // edge_index[1][e]
        atomicAdd(&cnt[d], 1);
    }
}

__global__ void dinv_kernel(const int* __restrict__ cnt, float* __restrict__ dinv,
                            const int* __restrict__ batch, int* __restrict__ pcnt, int N) {
    int stride = gridDim.x * blockDim.x;
    for (int n = blockIdx.x * blockDim.x + threadIdx.x; n < N; n += stride) {
        dinv[n] = rsqrtf((float)(cnt[n] + 1));  // deg includes self-loop
        atomicAdd(&pcnt[batch[n]], 1);
    }
}

__global__ void scan_sum(const int* __restrict__ cnt, int N, int* __restrict__ bsum) {
    int b = blockIdx.x;
    int chunk = (N + SCAN_B - 1) / SCAN_B;
    int lo = b * chunk, hi = min(lo + chunk, N);
    int s = 0;
    for (int i = lo + threadIdx.x; i < hi; i += SCAN_T) s += cnt[i];
    for (int off = 32; off; off >>= 1) s += __shfl_xor(s, off);
    __shared__ int red[SCAN_T / 64];
    int wave = threadIdx.x >> 6, lane = threadIdx.x & 63;
    if (lane == 0) red[wave] = s;
    __syncthreads();
    if (threadIdx.x == 0) {
        int t = 0;
        for (int w = 0; w < SCAN_T / 64; w++) t += red[w];
        bsum[b] = t;
    }
}

__global__ void scan_bsum(const int* __restrict__ bsum, int* __restrict__ bofs) {
    if (blockIdx.x == 0 && threadIdx.x == 0) {
        int r = 0;
        for (int b = 0; b < SCAN_B; b++) { bofs[b] = r; r += bsum[b]; }
    }
}

__global__ void scan_chunk(const int* __restrict__ cnt, int N, const int* __restrict__ bofs,
                           int* __restrict__ row_start, int* __restrict__ cursor) {
    int b = blockIdx.x;
    int chunk = (N + SCAN_B - 1) / SCAN_B;
    int lo = b * chunk, hi = min(lo + chunk, N);
    __shared__ int s[SCAN_T];
    __shared__ int carry;
    if (threadIdx.x == 0) carry = bofs[b];
    __syncthreads();
    for (int base = lo; base < hi; base += SCAN_T) {
        int i = base + threadIdx.x;
        int v = (i < hi) ? cnt[i] : 0;
        s[threadIdx.x] = v;
        __syncthreads();
        for (int off = 1; off < SCAN_T; off <<= 1) {
            int t = (threadIdx.x >= off) ? s[threadIdx.x - off] : 0;
            __syncthreads();
            s[threadIdx.x] += t;
            __syncthreads();
        }
        int incl = s[threadIdx.x];
        int c = carry;
        if (i < hi) {
            int ex = c + incl - v;
            row_start[i] = ex;
            cursor[i] = ex;
        }
        __syncthreads();
        if (threadIdx.x == SCAN_T - 1) carry = c + incl;
        __syncthreads();
    }
}

__global__ void fill_kernel(const int* __restrict__ ei, int E, const float* __restrict__ dinv,
                            int* __restrict__ cursor, int2* __restrict__ csr) {
    int stride = gridDim.x * blockDim.x;
    for (int e = blockIdx.x * blockDim.x + threadIdx.x; e < E; e += stride) {
        int s = ei[e];
        int d = ei[E + e];
        int pos = atomicAdd(&cursor[d], 1);
        csr[pos] = make_int2(s, __float_as_int(dinv[s]));
    }
}

// ---------------- quarter-split fused 64x64 matmul ----------------
__device__ __forceinline__ float4 qmatmul(float4 h4, const float* __restrict__ sW, int q, int sl) {
    float4 z4 = make_float4(0.f, 0.f, 0.f, 0.f);
#pragma unroll
    for (int t = 0; t < 16; t++) {
        int k = (q << 4) + t;
        int srclane = 20 * q + (t >> 2);
        float comp = ((t & 3) == 0) ? h4.x : ((t & 3) == 1) ? h4.y : ((t & 3) == 2) ? h4.z : h4.w;
        float hk = __shfl(comp, srclane);
        const float4 w4 = *reinterpret_cast<const float4*>(&sW[k * HID + sl * 4]);
        z4.x += hk * w4.x; z4.y += hk * w4.y; z4.z += hk * w4.z; z4.w += hk * w4.w;
    }
#pragma unroll
    for (int off = 16; off <= 32; off <<= 1) {
        z4.x += __shfl_xor(z4.x, off);
        z4.y += __shfl_xor(z4.y, off);
        z4.z += __shfl_xor(z4.z, off);
        z4.w += __shfl_xor(z4.w, off);
    }
    return z4;
}

// ---------------- Layer 1 ----------------

__global__ __launch_bounds__(256) void layer1_kernel(
    const float* __restrict__ x, const int2* __restrict__ csr,
    const int* __restrict__ row_start, const int* __restrict__ cnt, const float* __restrict__ dinv,
    const float* __restrict__ W1, const float* __restrict__ b1, const float* __restrict__ W2,
    float* __restrict__ z1, int N) {
    __shared__ float sW2[HID * HID];
    for (int i = threadIdx.x; i < HID * HID; i += 256) sW2[i] = W2[i];
    __syncthreads();
    int lane = threadIdx.x & 63;
    int q = lane >> 4, sl = lane & 15;
    int n = blockIdx.x * 4 + (threadIdx.x >> 6);
    if (n >= N) return;
    int start = row_start[n], deg = cnt[n];
    float acc = 0.f;
    for (int i = start + lane; i < start + deg; i += 64) {
        int2 ew = csr[i];
        acc += __int_as_float(ew.y) * x[ew.x];
    }
#pragma unroll
    for (int off = 32; off; off >>= 1) acc += __shfl_xor(acc, off);
    float dn = dinv[n];
    float p = dn * (acc + dn * x[n]);  // wave-uniform
    const float4 w14 = *reinterpret_cast<const float4*>(&W1[sl * 4]);
    const float4 b14 = *reinterpret_cast<const float4*>(&b1[sl * 4]);
    float4 h4;
    h4.x = fmaxf(p * w14.x + b14.x, 0.f);
    h4.y = fmaxf(p * w14.y + b14.y, 0.f);
    h4.z = fmaxf(p * w14.z + b14.z, 0.f);
    h4.w = fmaxf(p * w14.w + b14.w, 0.f);
    float4 z4 = qmatmul(h4, sW2, q, sl);
    if (q == 0) *reinterpret_cast<float4*>(&z1[(size_t)n * HID + sl * 4]) = z4;
}

// ---------------- 64-wide propagate (layers 2,3) ----------------
// Gather with 4 predicated loads in flight per quarter-chain.
// FUSE: out = relu(P(zin)+bias) @ W  (layer 2)
// POOL: segmented LDS reduction over the block's 4 (sorted-batch) nodes,
//       then one atomicAdd run per distinct graph id. (layer 3 + pool)

template <bool FUSE, bool POOL>
__global__ __launch_bounds__(256) void p64_kernel(
    const float* __restrict__ zin, const int2* __restrict__ csr,
    const int* __restrict__ row_start, const int* __restrict__ cnt, const float* __restrict__ dinv,
    const float* __restrict__ bias, const float* __restrict__ W,
    float* __restrict__ out, const int* __restrict__ batch, int N) {
    __shared__ float sW[FUSE ? HID * HID : 1];
    __shared__ float pbuf[POOL ? 4 : 1][POOL ? HID : 1];
    __shared__ int pg[4];
    if (FUSE) {
        for (int i = threadIdx.x; i < HID * HID; i += 256) sW[i] = W[i];
        __syncthreads();
    }
    int lane = threadIdx.x & 63;
    int wid = threadIdx.x >> 6;
    int q = lane >> 4, sl = lane & 15;
    int n = blockIdx.x * 4 + wid;
    bool valid = n < N;
    if (!POOL && !valid) return;

    float4 acc = make_float4(0.f, 0.f, 0.f, 0.f);
    if (valid) {
        int start = row_start[n], deg = cnt[n];
        float dn = dinv[n];
        const float4 self = *reinterpret_cast<const float4*>(&zin[(size_t)n * HID + (sl << 2)]);
        for (int base = 0; base < deg; base += 64) {
            int m = deg - base; if (m > 64) m = 64;
            int2 ew = (lane < m) ? csr[start + base + lane] : make_int2(0, 0);
            int mt = (m + 3) >> 2;
            for (int tb = 0; tb < mt; tb += 4) {
#pragma unroll
                for (int k = 0; k < 4; k++) {
                    int t = tb + k;
                    bool act = t < mt;
                    int eidx = ((t << 2) + q) & 63;
                    int ss = __shfl(ew.x, eidx);
                    float ww = __int_as_float(__shfl(ew.y, eidx));
                    ss = act ? ss : 0;
                    ww = act ? ww : 0.f;
                    const float4 row =
                        *reinterpret_cast<const float4*>(&zin[(size_t)ss * HID + (sl << 2)]);
                    acc.x += ww * row.x; acc.y += ww * row.y;
                    acc.z += ww * row.z; acc.w += ww * row.w;
                }
            }
        }
#pragma unroll
        for (int off = 16; off <= 32; off <<= 1) {
            acc.x += __shfl_xor(acc.x, off);
            acc.y += __shfl_xor(acc.y, off);
            acc.z += __shfl_xor(acc.z, off);
            acc.w += __shfl_xor(acc.w, off);
        }
        const float4 b4 = *reinterpret_cast<const float4*>(&bias[sl << 2]);
        acc.x = dn * (acc.x + dn * self.x) + b4.x;
        acc.y = dn * (acc.y + dn * self.y) + b4.y;
        acc.z = dn * (acc.z + dn * self.z) + b4.z;
        acc.w = dn * (acc.w + dn * self.w) + b4.w;
    }

    if (FUSE) {
        float4 h4;
        h4.x = fmaxf(acc.x, 0.f); h4.y = fmaxf(acc.y, 0.f);
        h4.z = fmaxf(acc.z, 0.f); h4.w = fmaxf(acc.w, 0.f);
        float4 z4 = qmatmul(h4, sW, q, sl);
        if (q == 0) *reinterpret_cast<float4*>(&out[(size_t)n * HID + (sl << 2)]) = z4;
    } else if (POOL) {
        if (q == 0) {
            *reinterpret_cast<float4*>(&pbuf[wid][sl << 2]) = acc;
            if (sl == 0) pg[wid] = valid ? batch[n] : -1;
        }
        __syncthreads();
        if (wid == 0) {
            int j = lane;
            float v = 0.f;
            int gp = -1;
#pragma unroll
            for (int w = 0; w < 4; w++) {
                int gw = pg[w];  // wave-uniform
                if (gw < 0) continue;
                if (gw == gp) {
                    v += pbuf[w][j];
                } else {
                    if (gp >= 0) atomicAdd(&out[(size_t)gp * HID + j], v);
                    v = pbuf[w][j];
                    gp = gw;
                }
            }
            if (gp >= 0) atomicAdd(&out[(size_t)gp * HID + j], v);
        }
    } else {
        if (q == 0) *reinterpret_cast<float4*>(&out[(size_t)n * HID + (sl << 2)]) = acc;
    }
}

// ---------------- head ----------------

__global__ void head_kernel(const float* __restrict__ psum, const int* __restrict__ pcnt,
                            const float* __restrict__ dist, const float* __restrict__ sw,
                            const float* __restrict__ Wl, const float* __restrict__ bl,
                            const float* __restrict__ Wl1, const float* __restrict__ bl1,
                            const float* __restrict__ Wl2, const float* __restrict__ bl2,
                            float* __restrict__ out, int G) {
    int g = blockIdx.x * blockDim.x + threadIdx.x;
    if (g >= G) return;
    float invc = 1.f / fmaxf((float)pcnt[g], 1.f);
    float a[5];
#pragma unroll
    for (int k = 0; k < 5; k++) a[k] = bl[k];
    for (int j = 0; j < HID; j++) {
        float p = psum[(size_t)g * HID + j] * invc;
#pragma unroll
        for (int k = 0; k < 5; k++) a[k] += p * Wl[j * 5 + k];
    }
    float g7[7];
#pragma unroll
    for (int k = 0; k < 5; k++) g7[k] = a[k];
    g7[5] = dist[g];
    g7[6] = sw[g];
    float r = bl2[0];
#pragma unroll
    for (int k2 = 0; k2 < 5; k2++) {
        float t = bl1[k2];
#pragma unroll
        for (int j = 0; j < 7; j++) t += g7[j] * Wl1[j * 5 + k2];
        t = fmaxf(t, 0.f);
        r += t * Wl2[k2];
    }
    out[g] = r;
}

// ---------------- launch ----------------

extern "C" void kernel_launch(void* const* d_in, const int* in_sizes, int n_in,
                              void* d_out, int out_size, void* d_ws, size_t ws_size,
                              hipStream_t stream) {
    const float* x    = (const float*)d_in[0];
    const int*   ei   = (const int*)d_in[1];
    const int*   batch= (const int*)d_in[2];
    const float* dist = (const float*)d_in[3];
    const float* sw   = (const float*)d_in[4];
    const float* W1   = (const float*)d_in[5];
    const float* b1   = (const float*)d_in[6];
    const float* W2   = (const float*)d_in[7];
    const float* b2   = (const float*)d_in[8];
    const float* W3   = (const float*)d_in[9];
    const float* b3   = (const float*)d_in[10];
    const float* Wl   = (const float*)d_in[11];
    const float* bl   = (const float*)d_in[12];
    const float* Wl1  = (const float*)d_in[13];
    const float* bl1  = (const float*)d_in[14];
    const float* Wl2  = (const float*)d_in[15];
    const float* bl2  = (const float*)d_in[16];

    int N = in_sizes[0];
    int E = in_sizes[1] / 2;
    int G = in_sizes[3];

    char* ws = (char*)d_ws;
    size_t off = 0;
    auto alloc = [&](size_t bytes) -> char* {
        char* p = ws + off;
        off += (bytes + 255) & ~(size_t)255;
        return p;
    };
    int*   cnt       = (int*)alloc((size_t)N * 4);
    int*   row_start = (int*)alloc((size_t)N * 4);
    int*   cursor    = (int*)alloc((size_t)N * 4);
    float* dinv      = (float*)alloc((size_t)N * 4);
    int*   bsum      = (int*)alloc(SCAN_B * 4);
    int*   bofs      = (int*)alloc(SCAN_B * 4);
    int2*  csr       = (int2*)alloc((size_t)E * 8);
    float* bufA      = (float*)alloc((size_t)N * HID * 4);
    float* bufB      = (float*)alloc((size_t)N * HID * 4);
    float* psum      = (float*)alloc((size_t)G * HID * 4);
    int*   pcnt      = (int*)alloc((size_t)G * 4);

    hipMemsetAsync(cnt, 0, (size_t)N * 4, stream);
    hipMemsetAsync(psum, 0, (size_t)G * HID * 4, stream);
    hipMemsetAsync(pcnt, 0, (size_t)G * 4, stream);

    count_kernel<<<2048, 256, 0, stream>>>(ei, E, cnt);
    dinv_kernel<<<(N + 255) / 256, 256, 0, stream>>>(cnt, dinv, batch, pcnt, N);
    scan_sum<<<SCAN_B, SCAN_T, 0, stream>>>(cnt, N, bsum);
    scan_bsum<<<1, 64, 0, stream>>>(bsum, bofs);
    scan_chunk<<<SCAN_B, SCAN_T, 0, stream>>>(cnt, N, bofs, row_start, cursor);
    fill_kernel<<<2048, 256, 0, stream>>>(ei, E, dinv, cursor, csr);

    int nb = (N + 3) / 4;
    layer1_kernel<<<nb, 256, 0, stream>>>(x, csr, row_start, cnt, dinv, W1, b1, W2, bufA, N);
    p64_kernel<true, false><<<nb, 256, 0, stream>>>(bufA, csr, row_start, cnt, dinv, b2, W3,
                                                    bufB, nullptr, N);
    p64_kernel<false, true><<<nb, 256, 0, stream>>>(bufB, csr, row_start, cnt, dinv, b3, nullptr,
                                                    psum, batch, N);
    head_kernel<<<(G + 255) / 256, 256, 0, stream>>>(psum, pcnt, dist, sw, Wl, bl, Wl1, bl1, Wl2,
                                                     bl2, (float*)d_out, G);
}

// Round 4
// 464.259 us; speedup vs baseline: 1.5941x; 1.0619x over previous
//
#include <hip/hip_runtime.h>

#define HID 64
#define WPAD 68
#define SCAN_B 128
#define SCAN_T 256
#define NXCD 8

// ---------------- CSR build (XCD-partitioned by dst range) ----------------
// Block b runs on XCD (b & 7) [round-robin mapping]; that XCD owns dst nodes
// [N*x/8, N*(x+1)/8). Each XCD's blocks rescan the whole edge list (L3-resident)
// and handle only their dst range -> CSR/cnt lines live in ONE local L2.

__global__ __launch_bounds__(256) void count_part(const int* __restrict__ ei, int E, int N,
                                                  int* __restrict__ cnt) {
    int xcd = blockIdx.x & (NXCD - 1);
    int sl = blockIdx.x >> 3;
    int nsl = gridDim.x >> 3;
    int nlo = (int)((long long)N * xcd / NXCD);
    int nhi = (int)((long long)N * (xcd + 1) / NXCD);
    int stride = nsl * blockDim.x;
    for (int e = sl * blockDim.x + threadIdx.x; e < E; e += stride) {
        int d = ei[E + e];
        if (d >= nlo && d < nhi) atomicAdd(&cnt[d], 1);
    }
}

__global__ __launch_bounds__(256) void fill_part(const int* __restrict__ ei, int E, int N,
                                                 const float* __restrict__ dinv,
                                                 int* __restrict__ cursor,
                                                 int2* __restrict__ csr) {
    int xcd = blockIdx.x & (NXCD - 1);
    int sl = blockIdx.x >> 3;
    int nsl = gridDim.x >> 3;
    int nlo = (int)((long long)N * xcd / NXCD);
    int nhi = (int)((long long)N * (xcd + 1) / NXCD);
    int stride = nsl * blockDim.x;
    for (int e = sl * blockDim.x + threadIdx.x; e < E; e += stride) {
        int d = ei[E + e];
        if (d >= nlo && d < nhi) {
            int s = ei[e];
            int pos = atomicAdd(&cursor[d], 1);
            csr[pos] = make_int2(s, __float_as_int(dinv[s]));
        }
    }
}

__global__ void dinv_kernel(const int* __restrict__ cnt, float* __restrict__ dinv,
                            const int* __restrict__ batch, int* __restrict__ pcnt, int N) {
    int stride = gridDim.x * blockDim.x;
    for (int n = blockIdx.x * blockDim.x + threadIdx.x; n < N; n += stride) {
        dinv[n] = rsqrtf((float)(cnt[n] + 1));  // deg includes self-loop
        atomicAdd(&pcnt[batch[n]], 1);
    }
}

__global__ void scan_sum(const int* __restrict__ cnt, int N, int* __restrict__ bsum) {
    int b = blockIdx.x;
    int chunk = (N + SCAN_B - 1) / SCAN_B;
    int lo = b * chunk, hi = min(lo + chunk, N);
    int s = 0;
    for (int i = lo + threadIdx.x; i < hi; i += SCAN_T) s += cnt[i];
    for (int off = 32; off; off >>= 1) s += __shfl_xor(s, off);
    __shared__ int red[SCAN_T / 64];
    int wave = threadIdx.x >> 6, lane = threadIdx.x & 63;
    if (lane == 0) red[wave] = s;
    __syncthreads();
    if (threadIdx.x == 0) {
        int t = 0;
        for (int w = 0; w < SCAN_T / 64; w++) t += red[w];
        bsum[b] = t;
    }
}

__global__ void scan_bsum(const int* __restrict__ bsum, int* __restrict__ bofs) {
    if (blockIdx.x == 0 && threadIdx.x == 0) {
        int r = 0;
        for (int b = 0; b < SCAN_B; b++) { bofs[b] = r; r += bsum[b]; }
    }
}

__global__ void scan_chunk(const int* __restrict__ cnt, int N, const int* __restrict__ bofs,
                           int* __restrict__ row_start, int* __restrict__ cursor) {
    int b = blockIdx.x;
    int chunk = (N + SCAN_B - 1) / SCAN_B;
    int lo = b * chunk, hi = min(lo + chunk, N);
    __shared__ int s[SCAN_T];
    __shared__ int carry;
    if (threadIdx.x == 0) carry = bofs[b];
    __syncthreads();
    for (int base = lo; base < hi; base += SCAN_T) {
        int i = base + threadIdx.x;
        int v = (i < hi) ? cnt[i] : 0;
        s[threadIdx.x] = v;
        __syncthreads();
        for (int off = 1; off < SCAN_T; off <<= 1) {
            int t = (threadIdx.x >= off) ? s[threadIdx.x - off] : 0;
            __syncthreads();
            s[threadIdx.x] += t;
            __syncthreads();
        }
        int incl = s[threadIdx.x];
        int c = carry;
        if (i < hi) {
            int ex = c + incl - v;
            row_start[i] = ex;
            cursor[i] = ex;
        }
        __syncthreads();
        if (threadIdx.x == SCAN_T - 1) carry = c + incl;
        __syncthreads();
    }
}

// ---------------- quarter-split fused 64x64 matmul (padded LDS stride) ----------------
__device__ __forceinline__ float4 qmatmul(float4 h4, const float* __restrict__ sW, int q, int sl) {
    float4 z4 = make_float4(0.f, 0.f, 0.f, 0.f);
#pragma unroll
    for (int t = 0; t < 16; t++) {
        int k = (q << 4) + t;
        int srclane = 20 * q + (t >> 2);
        float comp = ((t & 3) == 0) ? h4.x : ((t & 3) == 1) ? h4.y : ((t & 3) == 2) ? h4.z : h4.w;
        float hk = __shfl(comp, srclane);
        const float4 w4 = *reinterpret_cast<const float4*>(&sW[k * WPAD + sl * 4]);
        z4.x += hk * w4.x; z4.y += hk * w4.y; z4.z += hk * w4.z; z4.w += hk * w4.w;
    }
#pragma unroll
    for (int off = 16; off <= 32; off <<= 1) {
        z4.x += __shfl_xor(z4.x, off);
        z4.y += __shfl_xor(z4.y, off);
        z4.z += __shfl_xor(z4.z, off);
        z4.w += __shfl_xor(z4.w, off);
    }
    return z4;
}

__device__ __forceinline__ void stageW(const float* __restrict__ W, float* __restrict__ sW) {
    for (int i = threadIdx.x; i < HID * HID; i += 256) {
        int r = i >> 6, c = i & 63;
        sW[r * WPAD + c] = W[i];
    }
    __syncthreads();
}

// ---------------- Layer 1 ----------------

__global__ __launch_bounds__(256) void layer1_kernel(
    const float* __restrict__ x, const int2* __restrict__ csr,
    const int* __restrict__ row_start, const int* __restrict__ cnt, const float* __restrict__ dinv,
    const float* __restrict__ W1, const float* __restrict__ b1, const float* __restrict__ W2,
    float* __restrict__ z1, int N) {
    __shared__ float sW2[HID * WPAD];
    stageW(W2, sW2);
    int lane = threadIdx.x & 63;
    int q = lane >> 4, sl = lane & 15;
    int n = blockIdx.x * 4 + (threadIdx.x >> 6);
    if (n >= N) return;
    int start = row_start[n], deg = cnt[n];
    float acc = 0.f;
    for (int i = start + lane; i < start + deg; i += 64) {
        int2 ew = csr[i];
        acc += __int_as_float(ew.y) * x[ew.x];
    }
#pragma unroll
    for (int off = 32; off; off >>= 1) acc += __shfl_xor(acc, off);
    float dn = dinv[n];
    float p = dn * (acc + dn * x[n]);  // wave-uniform
    const float4 w14 = *reinterpret_cast<const float4*>(&W1[sl * 4]);
    const float4 b14 = *reinterpret_cast<const float4*>(&b1[sl * 4]);
    float4 h4;
    h4.x = fmaxf(p * w14.x + b14.x, 0.f);
    h4.y = fmaxf(p * w14.y + b14.y, 0.f);
    h4.z = fmaxf(p * w14.z + b14.z, 0.f);
    h4.w = fmaxf(p * w14.w + b14.w, 0.f);
    float4 z4 = qmatmul(h4, sW2, q, sl);
    if (q == 0) *reinterpret_cast<float4*>(&z1[(size_t)n * HID + sl * 4]) = z4;
}

// ---------------- 64-wide propagate (layers 2,3) ----------------

template <bool FUSE, bool POOL>
__global__ __launch_bounds__(256) void p64_kernel(
    const float* __restrict__ zin, const int2* __restrict__ csr,
    const int* __restrict__ row_start, const int* __restrict__ cnt, const float* __restrict__ dinv,
    const float* __restrict__ bias, const float* __restrict__ W,
    float* __restrict__ out, const int* __restrict__ batch, int N) {
    __shared__ float sW[FUSE ? HID * WPAD : 1];
    __shared__ float pbuf[POOL ? 4 : 1][POOL ? HID : 1];
    __shared__ int pg[4];
    if (FUSE) stageW(W, sW);
    int lane = threadIdx.x & 63;
    int wid = threadIdx.x >> 6;
    int q = lane >> 4, sl = lane & 15;
    int n = blockIdx.x * 4 + wid;
    bool valid = n < N;
    if (!POOL && !valid) return;

    float4 acc = make_float4(0.f, 0.f, 0.f, 0.f);
    if (valid) {
        int start = row_start[n], deg = cnt[n];
        float dn = dinv[n];
        const float4 self = *reinterpret_cast<const float4*>(&zin[(size_t)n * HID + (sl << 2)]);
        for (int base = 0; base < deg; base += 64) {
            int m = deg - base; if (m > 64) m = 64;
            int2 ew = (lane < m) ? csr[start + base + lane] : make_int2(0, 0);
            int mt = (m + 3) >> 2;
            for (int tb = 0; tb < mt; tb += 4) {
#pragma unroll
                for (int k = 0; k < 4; k++) {
                    int t = tb + k;
                    bool act = t < mt;
                    int eidx = ((t << 2) + q) & 63;
                    int ss = __shfl(ew.x, eidx);
                    float ww = __int_as_float(__shfl(ew.y, eidx));
                    ss = act ? ss : 0;
                    ww = act ? ww : 0.f;
                    const float4 row =
                        *reinterpret_cast<const float4*>(&zin[(size_t)ss * HID + (sl << 2)]);
                    acc.x += ww * row.x; acc.y += ww * row.y;
                    acc.z += ww * row.z; acc.w += ww * row.w;
                }
            }
        }
#pragma unroll
        for (int off = 16; off <= 32; off <<= 1) {
            acc.x += __shfl_xor(acc.x, off);
            acc.y += __shfl_xor(acc.y, off);
            acc.z += __shfl_xor(acc.z, off);
            acc.w += __shfl_xor(acc.w, off);
        }
        const float4 b4 = *reinterpret_cast<const float4*>(&bias[sl << 2]);
        acc.x = dn * (acc.x + dn * self.x) + b4.x;
        acc.y = dn * (acc.y + dn * self.y) + b4.y;
        acc.z = dn * (acc.z + dn * self.z) + b4.z;
        acc.w = dn * (acc.w + dn * self.w) + b4.w;
    }

    if (FUSE) {
        float4 h4;
        h4.x = fmaxf(acc.x, 0.f); h4.y = fmaxf(acc.y, 0.f);
        h4.z = fmaxf(acc.z, 0.f); h4.w = fmaxf(acc.w, 0.f);
        float4 z4 = qmatmul(h4, sW, q, sl);
        if (q == 0) *reinterpret_cast<float4*>(&out[(size_t)n * HID + (sl << 2)]) = z4;
    } else if (POOL) {
        if (q == 0) {
            *reinterpret_cast<float4*>(&pbuf[wid][sl << 2]) = acc;
            if (sl == 0) pg[wid] = valid ? batch[n] : -1;
        }
        __syncthreads();
        if (wid == 0) {
            int j = lane;
            float v = 0.f;
            int gp = -1;
#pragma unroll
            for (int w = 0; w < 4; w++) {
                int gw = pg[w];  // wave-uniform
                if (gw < 0) continue;
                if (gw == gp) {
                    v += pbuf[w][j];
                } else {
                    if (gp >= 0) atomicAdd(&out[(size_t)gp * HID + j], v);
                    v = pbuf[w][j];
                    gp = gw;
                }
            }
            if (gp >= 0) atomicAdd(&out[(size_t)gp * HID + j], v);
        }
    } else {
        if (q == 0) *reinterpret_cast<float4*>(&out[(size_t)n * HID + (sl << 2)]) = acc;
    }
}

// ---------------- head ----------------

__global__ void head_kernel(const float* __restrict__ psum, const int* __restrict__ pcnt,
                            const float* __restrict__ dist, const float* __restrict__ sw,
                            const float* __restrict__ Wl, const float* __restrict__ bl,
                            const float* __restrict__ Wl1, const float* __restrict__ bl1,
                            const float* __restrict__ Wl2, const float* __restrict__ bl2,
                            float* __restrict__ out, int G) {
    int g = blockIdx.x * blockDim.x + threadIdx.x;
    if (g >= G) return;
    float invc = 1.f / fmaxf((float)pcnt[g], 1.f);
    float a[5];
#pragma unroll
    for (int k = 0; k < 5; k++) a[k] = bl[k];
    for (int j = 0; j < HID; j++) {
        float p = psum[(size_t)g * HID + j] * invc;
#pragma unroll
        for (int k = 0; k < 5; k++) a[k] += p * Wl[j * 5 + k];
    }
    float g7[7];
#pragma unroll
    for (int k = 0; k < 5; k++) g7[k] = a[k];
    g7[5] = dist[g];
    g7[6] = sw[g];
    float r = bl2[0];
#pragma unroll
    for (int k2 = 0; k2 < 5; k2++) {
        float t = bl1[k2];
#pragma unroll
        for (int j = 0; j < 7; j++) t += g7[j] * Wl1[j * 5 + k2];
        t = fmaxf(t, 0.f);
        r += t * Wl2[k2];
    }
    out[g] = r;
}

// ---------------- launch ----------------

extern "C" void kernel_launch(void* const* d_in, const int* in_sizes, int n_in,
                              void* d_out, int out_size, void* d_ws, size_t ws_size,
                              hipStream_t stream) {
    const float* x    = (const float*)d_in[0];
    const int*   ei   = (const int*)d_in[1];
    const int*   batch= (const int*)d_in[2];
    const float* dist = (const float*)d_in[3];
    const float* sw   = (const float*)d_in[4];
    const float* W1   = (const float*)d_in[5];
    const float* b1   = (const float*)d_in[6];
    const float* W2   = (const float*)d_in[7];
    const float* b2   = (const float*)d_in[8];
    const float* W3   = (const float*)d_in[9];
    const float* b3   = (const float*)d_in[10];
    const float* Wl   = (const float*)d_in[11];
    const float* bl   = (const float*)d_in[12];
    const float* Wl1  = (const float*)d_in[13];
    const float* bl1  = (const float*)d_in[14];
    const float* Wl2  = (const float*)d_in[15];
    const float* bl2  = (const float*)d_in[16];

    int N = in_sizes[0];
    int E = in_sizes[1] / 2;
    int G = in_sizes[3];

    char* ws = (char*)d_ws;
    size_t off = 0;
    auto alloc = [&](size_t bytes) -> char* {
        char* p = ws + off;
        off += (bytes + 255) & ~(size_t)255;
        return p;
    };
    int*   cnt       = (int*)alloc((size_t)N * 4);
    int*   row_start = (int*)alloc((size_t)N * 4);
    int*   cursor    = (int*)alloc((size_t)N * 4);
    float* dinv      = (float*)alloc((size_t)N * 4);
    int*   bsum      = (int*)alloc(SCAN_B * 4);
    int*   bofs      = (int*)alloc(SCAN_B * 4);
    int2*  csr       = (int2*)alloc((size_t)E * 8);
    float* bufA      = (float*)alloc((size_t)N * HID * 4);
    float* bufB      = (float*)alloc((size_t)N * HID * 4);
    float* psum      = (float*)alloc((size_t)G * HID * 4);
    int*   pcnt      = (int*)alloc((size_t)G * 4);

    hipMemsetAsync(cnt, 0, (size_t)N * 4, stream);
    hipMemsetAsync(psum, 0, (size_t)G * HID * 4, stream);
    hipMemsetAsync(pcnt, 0, (size_t)G * 4, stream);

    count_part<<<2048, 256, 0, stream>>>(ei, E, N, cnt);
    dinv_kernel<<<(N + 255) / 256, 256, 0, stream>>>(cnt, dinv, batch, pcnt, N);
    scan_sum<<<SCAN_B, SCAN_T, 0, stream>>>(cnt, N, bsum);
    scan_bsum<<<1, 64, 0, stream>>>(bsum, bofs);
    scan_chunk<<<SCAN_B, SCAN_T, 0, stream>>>(cnt, N, bofs, row_start, cursor);
    fill_part<<<2048, 256, 0, stream>>>(ei, E, N, dinv, cursor, csr);

    int nb = (N + 3) / 4;
    layer1_kernel<<<nb, 256, 0, stream>>>(x, csr, row_start, cnt, dinv, W1, b1, W2, bufA, N);
    p64_kernel<true, false><<<nb, 256, 0, stream>>>(bufA, csr, row_start, cnt, dinv, b2, W3,
                                                    bufB, nullptr, N);
    p64_kernel<false, true><<<nb, 256, 0, stream>>>(bufB, csr, row_start, cnt, dinv, b3, nullptr,
                                                    psum, batch, N);
    head_kernel<<<(G + 255) / 256, 256, 0, stream>>>(psum, pcnt, dist, sw, Wl, bl, Wl1, bl1, Wl2,
                                                     bl2, (float*)d_out, G);
}